// Round 1
// baseline (96.531 us; speedup 1.0000x reference)
//
#include <hip/hip_runtime.h>

// Problem constants (from the reference): VOCAB=50000, D=256, B=4, R=64, C=64, T=32.
#define VOCAB_SZ 50000
#define EMB_D    256
#define N_CELLS  (4 * 64 * 64)   // B*R*C = 16384
#define TOK_T    32

// Kernel 1: s[v] = dot(E[v, :], W)  -- one wave (64 lanes) per vocab row.
// Each lane loads float4 of E and W (64 lanes * 4 = 256 = D), then butterfly
// shuffle-reduce across the 64-lane wave.
__global__ void __launch_bounds__(256)
vocab_dot_kernel(const float* __restrict__ E, const float* __restrict__ W,
                 float* __restrict__ s) {
    const int gtid = blockIdx.x * blockDim.x + threadIdx.x;
    const int row  = gtid >> 6;          // one wave per row
    const int lane = threadIdx.x & 63;
    if (row >= VOCAB_SZ) return;

    const float4 e = *reinterpret_cast<const float4*>(E + (size_t)row * EMB_D + lane * 4);
    const float4 w = *reinterpret_cast<const float4*>(W + lane * 4);
    float p = e.x * w.x + e.y * w.y + e.z * w.z + e.w * w.w;

    // 64-lane wave reduction
    #pragma unroll
    for (int off = 32; off > 0; off >>= 1)
        p += __shfl_xor(p, off);

    if (lane == 0) s[row] = p;
}

// Kernel 2: out[cell] = sum_t s[x[cell, t]] + b.  One thread per cell.
__global__ void __launch_bounds__(256)
cell_sum_kernel(const int* __restrict__ x, const float* __restrict__ s,
                const float* __restrict__ b, float* __restrict__ out) {
    const int cell = blockIdx.x * blockDim.x + threadIdx.x;
    if (cell >= N_CELLS) return;

    const int4* xp = reinterpret_cast<const int4*>(x + (size_t)cell * TOK_T);
    float acc = 0.0f;
    #pragma unroll
    for (int i = 0; i < TOK_T / 4; ++i) {
        const int4 v = xp[i];
        acc += s[v.x];
        acc += s[v.y];
        acc += s[v.z];
        acc += s[v.w];
    }
    out[cell] = acc + b[0];
}

extern "C" void kernel_launch(void* const* d_in, const int* in_sizes, int n_in,
                              void* d_out, int out_size, void* d_ws, size_t ws_size,
                              hipStream_t stream) {
    const int*   x = (const int*)d_in[0];    // [B,R,C,T] int32
    const float* E = (const float*)d_in[1];  // [VOCAB, D] f32
    const float* W = (const float*)d_in[2];  // [D] f32
    const float* b = (const float*)d_in[3];  // [1] f32
    float* out = (float*)d_out;              // [B,R,C] f32
    float* s   = (float*)d_ws;               // [VOCAB] f32 scratch (200 KB)

    // Kernel 1: 50000 rows, 1 wave/row, 4 waves/block -> 12500 blocks of 256.
    {
        const int waves_per_block = 256 / 64;
        const int grid = (VOCAB_SZ + waves_per_block - 1) / waves_per_block;
        vocab_dot_kernel<<<grid, 256, 0, stream>>>(E, W, s);
    }

    // Kernel 2: 16384 cells, 1 thread/cell -> 64 blocks of 256.
    {
        const int grid = (N_CELLS + 255) / 256;
        cell_sum_kernel<<<grid, 256, 0, stream>>>(x, s, b, out);
    }
}

// Round 2
// 93.091 us; speedup vs baseline: 1.0370x; 1.0370x over previous
//
#include <hip/hip_runtime.h>

// Problem constants: VOCAB=50000, D=256, B=4, R=64, C=64, T=32.
#define VOCAB_SZ 50000
#define EMB_D    256
#define N_CELLS  (4 * 64 * 64)   // B*R*C = 16384
#define TOK_T    32

// Kernel 1: s[v] = dot(E[v,:], W).
// 4 rows per wave: 16 lanes per row, each lane loads 16 floats (4x float4
// at col offsets 0/64/128/192), FMAs against hoisted W, then a 4-step
// shuffle reduce within the 16-lane group. Grid-stride over row-groups so
// W is loaded once per thread.
__global__ void __launch_bounds__(256)
vocab_dot_kernel(const float* __restrict__ E, const float* __restrict__ W,
                 float* __restrict__ s) {
    const int tid    = blockIdx.x * blockDim.x + threadIdx.x;
    const int wave   = tid >> 6;
    const int lane   = threadIdx.x & 63;
    const int sub    = lane & 15;   // lane within 16-lane row group
    const int grp    = lane >> 4;   // which of the 4 rows this wave handles
    const int nwaves = (gridDim.x * blockDim.x) >> 6;

    const float4 w0 = *reinterpret_cast<const float4*>(W +   0 + sub * 4);
    const float4 w1 = *reinterpret_cast<const float4*>(W +  64 + sub * 4);
    const float4 w2 = *reinterpret_cast<const float4*>(W + 128 + sub * 4);
    const float4 w3 = *reinterpret_cast<const float4*>(W + 192 + sub * 4);

    const int ngroups = VOCAB_SZ / 4;   // 12500, divides exactly
    for (int g = wave; g < ngroups; g += nwaves) {
        const int row = g * 4 + grp;
        const float* er = E + (size_t)row * EMB_D;
        const float4 e0 = *reinterpret_cast<const float4*>(er +   0 + sub * 4);
        const float4 e1 = *reinterpret_cast<const float4*>(er +  64 + sub * 4);
        const float4 e2 = *reinterpret_cast<const float4*>(er + 128 + sub * 4);
        const float4 e3 = *reinterpret_cast<const float4*>(er + 192 + sub * 4);

        float p = e0.x*w0.x + e0.y*w0.y + e0.z*w0.z + e0.w*w0.w;
        p      += e1.x*w1.x + e1.y*w1.y + e1.z*w1.z + e1.w*w1.w;
        p      += e2.x*w2.x + e2.y*w2.y + e2.z*w2.z + e2.w*w2.w;
        p      += e3.x*w3.x + e3.y*w3.y + e3.z*w3.z + e3.w*w3.w;

        // reduce across the 16-lane group
        p += __shfl_xor(p, 1);
        p += __shfl_xor(p, 2);
        p += __shfl_xor(p, 4);
        p += __shfl_xor(p, 8);

        if (sub == 0) s[row] = p;
    }
}

// Kernel 2: out[cell] = sum_t s[x[cell,t]] + b.
// 8 lanes per cell; each lane does ONE int4 load (4 tokens) -> fully
// coalesced x reads (consecutive lanes read consecutive 16B), 4 independent
// L2 gathers, 3-step shuffle reduce within the 8-lane group.
__global__ void __launch_bounds__(256)
cell_sum_kernel(const int* __restrict__ x, const float* __restrict__ s,
                const float* __restrict__ b, float* __restrict__ out) {
    const int tid = blockIdx.x * blockDim.x + threadIdx.x;  // 0 .. 131071
    if (tid >= N_CELLS * (TOK_T / 4)) return;

    const int4 v = reinterpret_cast<const int4*>(x)[tid];
    float acc = s[v.x] + s[v.y] + s[v.z] + s[v.w];

    acc += __shfl_xor(acc, 1);
    acc += __shfl_xor(acc, 2);
    acc += __shfl_xor(acc, 4);

    if ((threadIdx.x & 7) == 0) out[tid >> 3] = acc + b[0];
}

extern "C" void kernel_launch(void* const* d_in, const int* in_sizes, int n_in,
                              void* d_out, int out_size, void* d_ws, size_t ws_size,
                              hipStream_t stream) {
    const int*   x = (const int*)d_in[0];    // [B,R,C,T] int32
    const float* E = (const float*)d_in[1];  // [VOCAB, D] f32
    const float* W = (const float*)d_in[2];  // [D] f32
    const float* b = (const float*)d_in[3];  // [1] f32
    float* out = (float*)d_out;              // [B,R,C] f32
    float* s   = (float*)d_ws;               // [VOCAB] f32 scratch (200 KB)

    // Kernel 1: 1024 blocks * 4 waves = 4096 waves, ~3 row-groups each.
    vocab_dot_kernel<<<1024, 256, 0, stream>>>(E, W, s);

    // Kernel 2: 16384 cells * 8 lanes = 131072 threads -> 512 blocks.
    cell_sum_kernel<<<512, 256, 0, stream>>>(x, s, b, out);
}